// Round 9
// baseline (511.108 us; speedup 1.0000x reference)
//
#include <hip/hip_runtime.h>

#define HH 1024
#define WW 1024
#define BH 64
#define NSTEP 22          // 6 pipeline-fill + 16 emit steps (4 rows each)
#define DTC (0.1f/3.0f)

// Full-width row pipeline, 4 rows per step. Thread = 1 column.
// Step s: phase-1 reads halos of rows written at s-1 (u:Wu(s-1), lam:El(s-1),
// g:Eg(s-1)), updates 8-deep partial-sum rings, emits 4 rows per stage;
// phase-2 (after barrier) writes this step's rows. 2 barriers/step.
//   Wu(s) = by-6+4s+{0..3}   El(s) = by-12+4s+{0..3}
//   Eg(s) = by-18+4s+{0..3}  Eo(s) = by-24+4s+{0..3}  (stored for s>=6)
__global__ __launch_bounds__(1024, 4) void pde_band(
    const float* __restrict__ Uin,
    const float* __restrict__ K1,
    const float* __restrict__ K2,
    const float* __restrict__ Aw,
    float* __restrict__ Uout)
{
    __shared__ float4 shU [WW];   // 16 KB each, 64 KB total
    __shared__ float4 shL0[WW];
    __shared__ float4 shL1[WW];
    __shared__ float4 shG [WW];

    const int c  = threadIdx.x;
    const int by = blockIdx.x * BH;
    const size_t plane = (size_t)blockIdx.y * (size_t)(HH * WW);
    const float* __restrict__ Ub = Uin + plane;
    float* __restrict__ Ob = Uout + plane;

    float w0[25], w1[25], aw[25];
#pragma unroll
    for (int t = 0; t < 25; ++t) { w0[t] = K1[t]; w1[t] = K1[25 + t]; aw[t] = Aw[t]; }
    const float k2a = K2[0], k2b = K2[1];

    const int cm2 = (c - 2) & (WW - 1), cm1 = (c - 1) & (WW - 1);
    const int cp1 = (c + 1) & (WW - 1), cp2 = (c + 2) & (WW - 1);

    // 8-deep partial-sum rings (all indices compile-static via parity unroll)
    float pL0[8], pL1[8], pG[8], pV[8];
#pragma unroll
    for (int i = 0; i < 8; ++i) { pL0[i]=0.f; pL1[i]=0.f; pG[i]=0.f; pV[i]=0.f; }

    float uC[4]  = {0,0,0,0};   // centers of u rows Wu(s-1)
    float lC0[4] = {0,0,0,0};   // centers of lam rows El(s-1)
    float lC1[4] = {0,0,0,0};
    float gC[4]  = {0,0,0,0};   // centers of g rows Eg(s-1)

    const float4 z4 = {0.f, 0.f, 0.f, 0.f};
    shU[c] = z4; shL0[c] = z4; shL1[c] = z4; shG[c] = z4;
    __syncthreads();

    for (int sb = 0; sb < NSTEP / 2; ++sb) {
#pragma unroll
      for (int p = 0; p < 2; ++p) {
        const int s = 2 * sb + p;

        // issue global loads early (used at phase end; latency hides under FMA)
        float uS[4], idv[4];
#pragma unroll
        for (int q = 0; q < 4; ++q) {
          uS[q]  = Ub[(size_t)((unsigned)(by - 6  + 4*s + q) & (HH-1)) * WW + c];
          idv[q] = Ub[(size_t)((unsigned)(by - 24 + 4*s + q) & (HH-1)) * WW + c];
        }

        // ---- u halo rows Wu(s-1) -> lam ring; emit El(s) ----
        float nl0[4], nl1[4];
        {
          float4 h0 = shU[cm2], h1 = shU[cm1], h2 = shU[cp1], h3 = shU[cp2];
#pragma unroll
          for (int q = 0; q < 4; ++q) {
            const float uf[5] = {
              reinterpret_cast<const float*>(&h0)[q],
              reinterpret_cast<const float*>(&h1)[q],
              uC[q],
              reinterpret_cast<const float*>(&h2)[q],
              reinterpret_cast<const float*>(&h3)[q] };
#pragma unroll
            for (int t = 0; t < 5; ++t) {
              const int sl = (4*p + q + t + 4) & 7;
#pragma unroll
              for (int j = 0; j < 5; ++j) {
                pL0[sl] = fmaf(uf[j], w0[(4-t)*5 + j], pL0[sl]);
                pL1[sl] = fmaf(uf[j], w1[(4-t)*5 + j], pL1[sl]);
              }
            }
          }
#pragma unroll
          for (int k = 0; k < 4; ++k) {
            const int sl = (4*p + k + 4) & 7;
            nl0[k] = fmaxf(pL0[sl], 0.f) * k2a;  pL0[sl] = 0.f;
            nl1[k] = fmaxf(pL1[sl], 0.f) * k2b;  pL1[sl] = 0.f;
          }
        }

        // ---- lam halo rows El(s-1) -> grad ring; emit Eg(s) ----
        float ng[4];
        {
          float4 a0 = shL0[cm2], a1 = shL0[cm1], a2 = shL0[cp1], a3 = shL0[cp2];
          float4 b0 = shL1[cm2], b1 = shL1[cm1], b2 = shL1[cp1], b3 = shL1[cp2];
#pragma unroll
          for (int q = 0; q < 4; ++q) {
            const float lf0[5] = {
              reinterpret_cast<const float*>(&a0)[q],
              reinterpret_cast<const float*>(&a1)[q],
              lC0[q],
              reinterpret_cast<const float*>(&a2)[q],
              reinterpret_cast<const float*>(&a3)[q] };
            const float lf1[5] = {
              reinterpret_cast<const float*>(&b0)[q],
              reinterpret_cast<const float*>(&b1)[q],
              lC1[q],
              reinterpret_cast<const float*>(&b2)[q],
              reinterpret_cast<const float*>(&b3)[q] };
#pragma unroll
            for (int t = 0; t < 5; ++t) {
              const int sl = (4*p + q + t + 6) & 7;
#pragma unroll
              for (int j = 0; j < 5; ++j) {
                // conv_transpose weight: K1[ch][t][4-j]
                pG[sl] = fmaf(lf0[j], w0[t*5 + 4 - j], pG[sl]);
                pG[sl] = fmaf(lf1[j], w1[t*5 + 4 - j], pG[sl]);
              }
            }
          }
#pragma unroll
          for (int k = 0; k < 4; ++k) {
            const int sl = (4*p + k + 6) & 7;
            ng[k] = pG[sl];  pG[sl] = 0.f;
          }
        }

        // ---- g halo rows Eg(s-1) -> vec ring; emit/store Eo(s) ----
        {
          float4 g0 = shG[cm2], g1 = shG[cm1], g2 = shG[cp1], g3 = shG[cp2];
#pragma unroll
          for (int q = 0; q < 4; ++q) {
            const float gf[5] = {
              reinterpret_cast<const float*>(&g0)[q],
              reinterpret_cast<const float*>(&g1)[q],
              gC[q],
              reinterpret_cast<const float*>(&g2)[q],
              reinterpret_cast<const float*>(&g3)[q] };
#pragma unroll
            for (int t = 0; t < 5; ++t) {
              const int sl = (4*p + q + t) & 7;
#pragma unroll
              for (int j = 0; j < 5; ++j)
                pV[sl] = fmaf(gf[j], aw[(4-t)*5 + j], pV[sl]);
            }
          }
          if (s >= 6) {
#pragma unroll
            for (int k = 0; k < 4; ++k) {
              const int sl = (4*p + k) & 7;
              const int row = by - 24 + 4*s + k;      // in [by, by+63]
              Ob[(size_t)row * WW + c] = idv[k] + DTC * pV[sl];
              pV[sl] = 0.f;
            }
          } else {
#pragma unroll
            for (int k = 0; k < 4; ++k) pV[(4*p + k) & 7] = 0.f;
          }
        }

        __syncthreads();   // all reads of old rows complete

        shU[c]  = make_float4(uS[0], uS[1], uS[2], uS[3]);
        shL0[c] = make_float4(nl0[0], nl0[1], nl0[2], nl0[3]);
        shL1[c] = make_float4(nl1[0], nl1[1], nl1[2], nl1[3]);
        shG[c]  = make_float4(ng[0], ng[1], ng[2], ng[3]);

        __syncthreads();   // writes visible for next step's reads

#pragma unroll
        for (int q = 0; q < 4; ++q) {
          uC[q] = uS[q]; lC0[q] = nl0[q]; lC1[q] = nl1[q]; gC[q] = ng[q];
        }
      }
    }
}

extern "C" void kernel_launch(void* const* d_in, const int* in_sizes, int n_in,
                              void* d_out, int out_size, void* d_ws, size_t ws_size,
                              hipStream_t stream) {
    const float* U  = (const float*)d_in[0];
    const float* K1 = (const float*)d_in[1];
    const float* K2 = (const float*)d_in[2];
    const float* Aw = (const float*)d_in[3];
    float* out = (float*)d_out;
    float* ws  = (float*)d_ws;

    const int B = in_sizes[0] / (HH * WW);   // 16
    dim3 grid(HH / BH, B);                   // 16 bands x 16 images = 256 blocks

    // 3 Euler layers; ping-pong in -> out -> ws -> out
    pde_band<<<grid, 1024, 0, stream>>>(U,   K1, K2, Aw, out);
    pde_band<<<grid, 1024, 0, stream>>>(out, K1, K2, Aw, ws);
    pde_band<<<grid, 1024, 0, stream>>>(ws,  K1, K2, Aw, out);
}